// Round 6
// baseline (244.724 us; speedup 1.0000x reference)
//
#include <hip/hip_runtime.h>

#define TT 25000
#define BB 2
#define CC 128
#define NN (BB*TT)   // 50000 nodes
#define NB ((NN + 255) / 256)  // 196 scan blocks

__device__ inline unsigned short f2bf(float f) {
    unsigned int u = __float_as_uint(f);
    u += 0x7FFF + ((u >> 16) & 1);          // round-to-nearest-even
    return (unsigned short)(u >> 16);
}

// ---------------- degree count + per-edge sequence number ----------------
__global__ __launch_bounds__(256) void k_deg(const int* __restrict__ dst, int E,
                                             int* __restrict__ deg,
                                             int* __restrict__ eseq) {
    int i0 = blockIdx.x * 512 + threadIdx.x;
    int i1 = i0 + 256;
    int d0 = 0, d1 = 0;
    bool ok0 = (i0 < E), ok1 = (i1 < E);
    if (ok0) d0 = dst[i0];
    if (ok1) d1 = dst[i1];
    if (ok0) eseq[i0] = atomicAdd(&deg[d0], 1);
    if (ok1) eseq[i1] = atomicAdd(&deg[d1], 1);
}

// ---------------- scan pass 1: per-block sums ----------------
__global__ __launch_bounds__(256) void k_bsum(const int* __restrict__ deg,
                                              int* __restrict__ bsum) {
    __shared__ int red[256];
    int tid = threadIdx.x;
    int i = blockIdx.x * 256 + tid;
    red[tid] = (i < NN) ? deg[i] : 0;
    __syncthreads();
#pragma unroll
    for (int o = 128; o > 0; o >>= 1) {
        if (tid < o) red[tid] += red[tid + o];
        __syncthreads();
    }
    if (tid == 0) bsum[blockIdx.x] = red[0];
}

// ---------------- scan pass 2: block prefix + local scan + dinv ----------------
__global__ __launch_bounds__(256) void k_scan2(const int* __restrict__ deg,
                                               const int* __restrict__ bsum,
                                               int* __restrict__ off,
                                               float* __restrict__ dinv) {
    __shared__ int part[256];
    __shared__ int bpref;
    int tid = threadIdx.x;
    int i = blockIdx.x * 256 + tid;

    part[tid] = (tid < NB && tid < blockIdx.x) ? bsum[tid] : 0;
    __syncthreads();
#pragma unroll
    for (int o = 128; o > 0; o >>= 1) {
        if (tid < o) part[tid] += part[tid + o];
        __syncthreads();
    }
    if (tid == 0) bpref = part[0];
    __syncthreads();
    int base = bpref;
    __syncthreads();

    int v = (i < NN) ? deg[i] : 0;
    part[tid] = v;
    __syncthreads();
#pragma unroll
    for (int o = 1; o < 256; o <<= 1) {
        int u = (tid >= o) ? part[tid - o] : 0;
        __syncthreads();
        part[tid] += u;
        __syncthreads();
    }
    int incl = part[tid];
    if (i < NN) {
        off[i]  = base + incl - v;                  // exclusive
        dinv[i] = rsqrtf((float)(v + 1));
    }
    if (i == NN - 1) off[NN] = base + incl;         // == E
}

// ---------------- CSR fill: atomic-free scatter ----------------
__global__ __launch_bounds__(256) void k_fill(const int* __restrict__ src,
                                              const int* __restrict__ dst, int E,
                                              const int* __restrict__ off,
                                              const int* __restrict__ eseq,
                                              int* __restrict__ csr_src) {
    int i = blockIdx.x * blockDim.x + threadIdx.x;
    if (i < E) {
        int d = dst[i];
        csr_src[off[d] + eseq[i]] = src[i];
    }
}

// ---------------- GEMM: 128x128 tile, 8x8 thread tile, h in bf16 ----------------
#define GBN 128
#define GBK 32
__global__ __launch_bounds__(256) void k_gemm(const float* __restrict__ x,
                                              const float* __restrict__ W,
                                              unsigned short* __restrict__ h) {
    __shared__ float xs[GBK][GBN + 4];              // 16.9 KB
    __shared__ float ws[GBK][CC + 4];               // 16.9 KB
    int tid = threadIdx.x;
    int n0 = blockIdx.x * GBN;

    // loaders: 128 lanes x 2 c-rows, 16 passes each
    int nl = tid & 127;
    int cl = tid >> 7;                              // 0..1
    int n = n0 + nl;
    bool ok = (n < NN);
    int b = 0, t = 0;
    if (ok) { b = n / TT; t = n - b * TT; }
    const float* xp = x + ((size_t)b * CC) * TT + t;

    int tx = tid & 15;                              // oc/8
    int ty = tid >> 4;                              // node/8

    float acc[8][8];
#pragma unroll
    for (int i = 0; i < 8; ++i)
#pragma unroll
        for (int j = 0; j < 8; ++j) acc[i][j] = 0.f;

    for (int k0 = 0; k0 < CC; k0 += GBK) {
#pragma unroll
        for (int i = 0; i < GBK / 2; ++i) {
            int c = cl + i * 2;
            xs[c][nl] = ok ? xp[(size_t)(k0 + c) * TT] : 0.f;
            ws[c][nl] = W[(k0 + c) * CC + nl];
        }
        __syncthreads();
#pragma unroll 4
        for (int k = 0; k < GBK; ++k) {
            float4 a0 = *(const float4*)&xs[k][ty * 8];
            float4 a1 = *(const float4*)&xs[k][ty * 8 + 4];
            float4 b0 = *(const float4*)&ws[k][tx * 8];
            float4 b1 = *(const float4*)&ws[k][tx * 8 + 4];
            float av[8] = {a0.x, a0.y, a0.z, a0.w, a1.x, a1.y, a1.z, a1.w};
            float bv[8] = {b0.x, b0.y, b0.z, b0.w, b1.x, b1.y, b1.z, b1.w};
#pragma unroll
            for (int i = 0; i < 8; ++i)
#pragma unroll
                for (int j = 0; j < 8; ++j)
                    acc[i][j] = fmaf(av[i], bv[j], acc[i][j]);
        }
        __syncthreads();
    }

#pragma unroll
    for (int i = 0; i < 8; ++i) {
        int no = n0 + ty * 8 + i;
        if (no < NN) {
            ushort4 p0, p1;
            p0.x = f2bf(acc[i][0]); p0.y = f2bf(acc[i][1]);
            p0.z = f2bf(acc[i][2]); p0.w = f2bf(acc[i][3]);
            p1.x = f2bf(acc[i][4]); p1.y = f2bf(acc[i][5]);
            p1.z = f2bf(acc[i][6]); p1.w = f2bf(acc[i][7]);
            *(ushort4*)&h[(size_t)no * CC + tx * 8]     = p0;
            *(ushort4*)&h[(size_t)no * CC + tx * 8 + 4] = p1;
        }
    }
}

// ---------------- fused aggregation + transpose-out ----------------
// Block = 256 threads (4 waves), 64 consecutive nodes. Wave w computes nodes
// w*16+j (2 ch/lane), stores to LDS tile [t_local][oc]; flush writes out
// coalesced: wave w writes oc = w+4*it rows, 64 consecutive t per instr.
__global__ __launch_bounds__(256) void k_aggt(const unsigned int* __restrict__ hb,
                                              const int* __restrict__ off,
                                              const int* __restrict__ csr_src,
                                              const float* __restrict__ dinv,
                                              const float* __restrict__ bias,
                                              float* __restrict__ out) {
    __shared__ __align__(16) float tile[64][130];   // 32.5 KB
    int tid  = threadIdx.x;
    int lane = tid & 63;
    int w    = tid >> 6;
    int n0   = blockIdx.x * 64;
    const float2* b2 = (const float2*)bias;
    float2 bb = b2[lane];

    for (int j = 0; j < 16; ++j) {
        int tl = w * 16 + j;
        int n  = n0 + tl;
        if (n < NN) {
            float ax = 0.f, ay = 0.f;
            int e0 = off[n], e1 = off[n + 1];
            int e = e0;
            for (; e + 4 <= e1; e += 4) {
                int s0 = csr_src[e],     s1 = csr_src[e + 1];
                int s2 = csr_src[e + 2], s3 = csr_src[e + 3];
                float f0 = dinv[s0], f1 = dinv[s1], f2 = dinv[s2], f3 = dinv[s3];
                unsigned int v0 = hb[(size_t)s0 * 64 + lane];
                unsigned int v1 = hb[(size_t)s1 * 64 + lane];
                unsigned int v2 = hb[(size_t)s2 * 64 + lane];
                unsigned int v3 = hb[(size_t)s3 * 64 + lane];
                ax = fmaf(f0, __uint_as_float(v0 << 16), ax);
                ay = fmaf(f0, __uint_as_float(v0 & 0xFFFF0000u), ay);
                ax = fmaf(f1, __uint_as_float(v1 << 16), ax);
                ay = fmaf(f1, __uint_as_float(v1 & 0xFFFF0000u), ay);
                ax = fmaf(f2, __uint_as_float(v2 << 16), ax);
                ay = fmaf(f2, __uint_as_float(v2 & 0xFFFF0000u), ay);
                ax = fmaf(f3, __uint_as_float(v3 << 16), ax);
                ay = fmaf(f3, __uint_as_float(v3 & 0xFFFF0000u), ay);
            }
            for (; e < e1; ++e) {
                int s = csr_src[e];
                float f = dinv[s];
                unsigned int v = hb[(size_t)s * 64 + lane];
                ax = fmaf(f, __uint_as_float(v << 16), ax);
                ay = fmaf(f, __uint_as_float(v & 0xFFFF0000u), ay);
            }
            float di = dinv[n];
            unsigned int hv = hb[(size_t)n * 64 + lane];
            float hx = __uint_as_float(hv << 16);
            float hy = __uint_as_float(hv & 0xFFFF0000u);
            float rx = fmaf(di, ax, di * di * hx) + bb.x;
            float ry = fmaf(di, ay, di * di * hy) + bb.y;
            *(float2*)&tile[tl][2 * lane] = make_float2(fmaxf(rx, 0.f), fmaxf(ry, 0.f));
        }
    }
    __syncthreads();

    int tl = tid & 63;
    int n  = n0 + tl;
    if (n < NN) {
        int b = n / TT, t = n - b * TT;
        float* op = out + (size_t)b * CC * TT + t;
#pragma unroll
        for (int it = 0; it < 32; ++it) {
            int oc = (tid >> 6) + it * 4;
            op[(size_t)oc * TT] = tile[tl][oc];
        }
    }
}

extern "C" void kernel_launch(void* const* d_in, const int* in_sizes, int n_in,
                              void* d_out, int out_size, void* d_ws, size_t ws_size,
                              hipStream_t stream) {
    const float* x    = (const float*)d_in[0];
    const float* W    = (const float*)d_in[1];
    const float* bias = (const float*)d_in[2];
    const int*   ei   = (const int*)d_in[3];
    int E = in_sizes[3] / 2;
    const int* src = ei;
    const int* dst = ei + E;
    float* out = (float*)d_out;

    char* ws = (char*)d_ws;
    size_t o = 0;
    unsigned short* h = (unsigned short*)(ws + o); o += (size_t)NN * CC * 2;  // 12.8 MB
    int*   deg  = (int*)  (ws + o); o += (size_t)NN * 4;
    float* dinv = (float*)(ws + o); o += (size_t)NN * 4;
    int*   off  = (int*)  (ws + o); o += (size_t)(NN + 1) * 4 + 12;
    int*   bsum = (int*)  (ws + o); o += (size_t)((NB + 3) & ~3) * 4;
    int*   eseq = (int*)  (ws + o); o += (size_t)E * 4;
    int*   csrs = (int*)  (ws + o); o += (size_t)E * 4;

    hipMemsetAsync(deg, 0, (size_t)NN * 4, stream);

    k_deg  <<<(E + 511) / 512, 256, 0, stream>>>(dst, E, deg, eseq);
    k_bsum <<<NB, 256, 0, stream>>>(deg, bsum);
    k_scan2<<<NB, 256, 0, stream>>>(deg, bsum, off, dinv);
    k_fill <<<(E + 255) / 256, 256, 0, stream>>>(src, dst, E, off, eseq, csrs);
    k_gemm <<<(NN + GBN - 1) / GBN, 256, 0, stream>>>(x, W, h);
    k_aggt <<<(NN + 63) / 64, 256, 0, stream>>>((const unsigned int*)h, off, csrs, dinv, bias, out);
}

// Round 7
// 227.633 us; speedup vs baseline: 1.0751x; 1.0751x over previous
//
#include <hip/hip_runtime.h>

#define TT 25000
#define BB 2
#define CC 128
#define NN (BB*TT)   // 50000 nodes
#define NB ((NN + 255) / 256)  // 196 scan blocks

__device__ inline unsigned short f2bf(float f) {
    unsigned int u = __float_as_uint(f);
    u += 0x7FFF + ((u >> 16) & 1);          // round-to-nearest-even
    return (unsigned short)(u >> 16);
}
__device__ inline float bfhi(unsigned int v) { return __uint_as_float(v << 16); }
__device__ inline float bflo(unsigned int v) { return __uint_as_float(v & 0xFFFF0000u); }

// ---------------- degree count + per-edge sequence number ----------------
__global__ __launch_bounds__(256) void k_deg(const int* __restrict__ dst, int E,
                                             int* __restrict__ deg,
                                             int* __restrict__ eseq) {
    int i0 = blockIdx.x * 512 + threadIdx.x;
    int i1 = i0 + 256;
    int d0 = 0, d1 = 0;
    bool ok0 = (i0 < E), ok1 = (i1 < E);
    if (ok0) d0 = dst[i0];
    if (ok1) d1 = dst[i1];
    if (ok0) eseq[i0] = atomicAdd(&deg[d0], 1);
    if (ok1) eseq[i1] = atomicAdd(&deg[d1], 1);
}

// ---------------- scan pass 1: per-block sums ----------------
__global__ __launch_bounds__(256) void k_bsum(const int* __restrict__ deg,
                                              int* __restrict__ bsum) {
    __shared__ int red[256];
    int tid = threadIdx.x;
    int i = blockIdx.x * 256 + tid;
    red[tid] = (i < NN) ? deg[i] : 0;
    __syncthreads();
#pragma unroll
    for (int o = 128; o > 0; o >>= 1) {
        if (tid < o) red[tid] += red[tid + o];
        __syncthreads();
    }
    if (tid == 0) bsum[blockIdx.x] = red[0];
}

// ---------------- scan pass 2: block prefix + local scan + dinv ----------------
__global__ __launch_bounds__(256) void k_scan2(const int* __restrict__ deg,
                                               const int* __restrict__ bsum,
                                               int* __restrict__ off,
                                               float* __restrict__ dinv) {
    __shared__ int part[256];
    __shared__ int bpref;
    int tid = threadIdx.x;
    int i = blockIdx.x * 256 + tid;

    part[tid] = (tid < NB && tid < blockIdx.x) ? bsum[tid] : 0;
    __syncthreads();
#pragma unroll
    for (int o = 128; o > 0; o >>= 1) {
        if (tid < o) part[tid] += part[tid + o];
        __syncthreads();
    }
    if (tid == 0) bpref = part[0];
    __syncthreads();
    int base = bpref;
    __syncthreads();

    int v = (i < NN) ? deg[i] : 0;
    part[tid] = v;
    __syncthreads();
#pragma unroll
    for (int o = 1; o < 256; o <<= 1) {
        int u = (tid >= o) ? part[tid - o] : 0;
        __syncthreads();
        part[tid] += u;
        __syncthreads();
    }
    int incl = part[tid];
    if (i < NN) {
        off[i]  = base + incl - v;                  // exclusive
        dinv[i] = rsqrtf((float)(v + 1));
    }
    if (i == NN - 1) off[NN] = base + incl;         // == E
}

// ---------------- CSR fill: atomic-free scatter ----------------
__global__ __launch_bounds__(256) void k_fill(const int* __restrict__ src,
                                              const int* __restrict__ dst, int E,
                                              const int* __restrict__ off,
                                              const int* __restrict__ eseq,
                                              int* __restrict__ csr_src) {
    int i = blockIdx.x * blockDim.x + threadIdx.x;
    if (i < E) {
        int d = dst[i];
        csr_src[off[d] + eseq[i]] = src[i];
    }
}

// ---------------- GEMM: 128x128 tile, 8x8 thread tile; stores h' = dinv*h (bf16) ----------------
#define GBN 128
#define GBK 32
__global__ __launch_bounds__(256) void k_gemm(const float* __restrict__ x,
                                              const float* __restrict__ W,
                                              const float* __restrict__ dinv,
                                              unsigned short* __restrict__ h) {
    __shared__ float xs[GBK][GBN + 4];
    __shared__ float ws[GBK][CC + 4];
    int tid = threadIdx.x;
    int n0 = blockIdx.x * GBN;

    int nl = tid & 127;
    int cl = tid >> 7;                              // 0..1
    int n = n0 + nl;
    bool ok = (n < NN);
    int b = 0, t = 0;
    if (ok) { b = n / TT; t = n - b * TT; }
    const float* xp = x + ((size_t)b * CC) * TT + t;

    int tx = tid & 15;                              // oc/8
    int ty = tid >> 4;                              // node/8

    float acc[8][8];
#pragma unroll
    for (int i = 0; i < 8; ++i)
#pragma unroll
        for (int j = 0; j < 8; ++j) acc[i][j] = 0.f;

    for (int k0 = 0; k0 < CC; k0 += GBK) {
#pragma unroll
        for (int i = 0; i < GBK / 2; ++i) {
            int c = cl + i * 2;
            xs[c][nl] = ok ? xp[(size_t)(k0 + c) * TT] : 0.f;
            ws[c][nl] = W[(k0 + c) * CC + nl];
        }
        __syncthreads();
#pragma unroll 4
        for (int k = 0; k < GBK; ++k) {
            float4 a0 = *(const float4*)&xs[k][ty * 8];
            float4 a1 = *(const float4*)&xs[k][ty * 8 + 4];
            float4 b0 = *(const float4*)&ws[k][tx * 8];
            float4 b1 = *(const float4*)&ws[k][tx * 8 + 4];
            float av[8] = {a0.x, a0.y, a0.z, a0.w, a1.x, a1.y, a1.z, a1.w};
            float bv[8] = {b0.x, b0.y, b0.z, b0.w, b1.x, b1.y, b1.z, b1.w};
#pragma unroll
            for (int i = 0; i < 8; ++i)
#pragma unroll
                for (int j = 0; j < 8; ++j)
                    acc[i][j] = fmaf(av[i], bv[j], acc[i][j]);
        }
        __syncthreads();
    }

#pragma unroll
    for (int i = 0; i < 8; ++i) {
        int no = n0 + ty * 8 + i;
        if (no < NN) {
            float di = dinv[no];
            ushort4 p0, p1;
            p0.x = f2bf(di * acc[i][0]); p0.y = f2bf(di * acc[i][1]);
            p0.z = f2bf(di * acc[i][2]); p0.w = f2bf(di * acc[i][3]);
            p1.x = f2bf(di * acc[i][4]); p1.y = f2bf(di * acc[i][5]);
            p1.z = f2bf(di * acc[i][6]); p1.w = f2bf(di * acc[i][7]);
            *(ushort4*)&h[(size_t)no * CC + tx * 8]     = p0;
            *(ushort4*)&h[(size_t)no * CC + tx * 8 + 4] = p1;
        }
    }
}

// ---------------- aggregation: one wave per node, unroll-8 CSR gather (pre-scaled bf16 h') ----------------
// out_n = dinv[n] * (sum_j h'[s_j] + h'[n]) + bias
__global__ __launch_bounds__(256) void k_agg(const unsigned int* __restrict__ hb,
                                             const int* __restrict__ off,
                                             const int* __restrict__ csr_src,
                                             const float* __restrict__ dinv,
                                             const float* __restrict__ bias,
                                             float* __restrict__ agg) {
    int lane = threadIdx.x & 63;
    int w    = threadIdx.x >> 6;
    int n    = blockIdx.x * 4 + w;
    if (n >= NN) return;
    float ax = 0.f, ay = 0.f;
    int e0 = off[n], e1 = off[n + 1];
    int e = e0;
    for (; e + 8 <= e1; e += 8) {
        int s0 = csr_src[e + 0], s1 = csr_src[e + 1], s2 = csr_src[e + 2], s3 = csr_src[e + 3];
        int s4 = csr_src[e + 4], s5 = csr_src[e + 5], s6 = csr_src[e + 6], s7 = csr_src[e + 7];
        unsigned int v0 = hb[(size_t)s0 * 64 + lane];
        unsigned int v1 = hb[(size_t)s1 * 64 + lane];
        unsigned int v2 = hb[(size_t)s2 * 64 + lane];
        unsigned int v3 = hb[(size_t)s3 * 64 + lane];
        unsigned int v4 = hb[(size_t)s4 * 64 + lane];
        unsigned int v5 = hb[(size_t)s5 * 64 + lane];
        unsigned int v6 = hb[(size_t)s6 * 64 + lane];
        unsigned int v7 = hb[(size_t)s7 * 64 + lane];
        ax += bfhi(v0); ay += bflo(v0);
        ax += bfhi(v1); ay += bflo(v1);
        ax += bfhi(v2); ay += bflo(v2);
        ax += bfhi(v3); ay += bflo(v3);
        ax += bfhi(v4); ay += bflo(v4);
        ax += bfhi(v5); ay += bflo(v5);
        ax += bfhi(v6); ay += bflo(v6);
        ax += bfhi(v7); ay += bflo(v7);
    }
    for (; e < e1; ++e) {
        int s = csr_src[e];
        unsigned int v = hb[(size_t)s * 64 + lane];
        ax += bfhi(v); ay += bflo(v);
    }
    unsigned int hv = hb[(size_t)n * 64 + lane];
    ax += bfhi(hv);
    ay += bflo(hv);
    float di = dinv[n];
    const float2* b2 = (const float2*)bias;
    float2 bb = b2[lane];
    float rx = fmaxf(fmaf(di, ax, bb.x), 0.f);
    float ry = fmaxf(fmaf(di, ay, bb.y), 0.f);
    ((float2*)agg)[(size_t)n * 64 + lane] = make_float2(rx, ry);
}

// ---------------- transpose [n][oc] -> [b][oc][t] ----------------
__global__ void k_trans(const float* __restrict__ agg, float* __restrict__ out) {
    __shared__ float tile[32][33];
    int t0 = blockIdx.x * 32;
    int o0 = blockIdx.y * 32;
    int b  = blockIdx.z;
    int tx = threadIdx.x, ty = threadIdx.y;         // 32 x 8
#pragma unroll
    for (int i = 0; i < 4; ++i) {
        int t = t0 + ty + i * 8;
        if (t < TT) tile[ty + i * 8][tx] = agg[(size_t)(b * TT + t) * CC + o0 + tx];
    }
    __syncthreads();
#pragma unroll
    for (int i = 0; i < 4; ++i) {
        int t  = t0 + tx;
        int oc = o0 + ty + i * 8;
        if (t < TT) out[((size_t)b * CC + oc) * TT + t] = tile[tx][ty + i * 8];
    }
}

extern "C" void kernel_launch(void* const* d_in, const int* in_sizes, int n_in,
                              void* d_out, int out_size, void* d_ws, size_t ws_size,
                              hipStream_t stream) {
    const float* x    = (const float*)d_in[0];
    const float* W    = (const float*)d_in[1];
    const float* bias = (const float*)d_in[2];
    const int*   ei   = (const int*)d_in[3];
    int E = in_sizes[3] / 2;
    const int* src = ei;
    const int* dst = ei + E;
    float* out = (float*)d_out;

    char* ws = (char*)d_ws;
    size_t o = 0;
    unsigned short* h = (unsigned short*)(ws + o); o += (size_t)NN * CC * 2;  // 12.8 MB
    float* agg  = (float*)(ws + o); o += (size_t)NN * CC * 4;                 // 25.6 MB
    int*   deg  = (int*)  (ws + o); o += (size_t)NN * 4;
    float* dinv = (float*)(ws + o); o += (size_t)NN * 4;
    int*   off  = (int*)  (ws + o); o += (size_t)(NN + 1) * 4 + 12;
    int*   bsum = (int*)  (ws + o); o += (size_t)((NB + 3) & ~3) * 4;
    int*   eseq = (int*)  (ws + o); o += (size_t)E * 4;
    int*   csrs = (int*)  (ws + o); o += (size_t)E * 4;

    hipMemsetAsync(deg, 0, (size_t)NN * 4, stream);

    k_deg  <<<(E + 511) / 512, 256, 0, stream>>>(dst, E, deg, eseq);
    k_bsum <<<NB, 256, 0, stream>>>(deg, bsum);
    k_scan2<<<NB, 256, 0, stream>>>(deg, bsum, off, dinv);
    k_fill <<<(E + 255) / 256, 256, 0, stream>>>(src, dst, E, off, eseq, csrs);
    k_gemm <<<(NN + GBN - 1) / GBN, 256, 0, stream>>>(x, W, dinv, h);
    k_agg  <<<(NN + 3) / 4, 256, 0, stream>>>((const unsigned int*)h, off, csrs, dinv, bias, agg);
    dim3 tg((TT + 31) / 32, CC / 32, BB);
    k_trans<<<tg, dim3(32, 8), 0, stream>>>(agg, out);
}

// Round 8
// 215.866 us; speedup vs baseline: 1.1337x; 1.0545x over previous
//
#include <hip/hip_runtime.h>

#define TT 25000
#define BB 2
#define CC 128
#define NN (BB*TT)   // 50000 nodes
#define NB ((NN + 255) / 256)  // 196 scan blocks

__device__ inline unsigned short f2bf(float f) {
    unsigned int u = __float_as_uint(f);
    u += 0x7FFF + ((u >> 16) & 1);          // round-to-nearest-even
    return (unsigned short)(u >> 16);
}
__device__ inline float bfhi(unsigned int v) { return __uint_as_float(v << 16); }
__device__ inline float bflo(unsigned int v) { return __uint_as_float(v & 0xFFFF0000u); }

// ---------------- degree count + per-edge sequence number ----------------
__global__ __launch_bounds__(256) void k_deg(const int* __restrict__ dst, int E,
                                             int* __restrict__ deg,
                                             int* __restrict__ eseq) {
    int i0 = blockIdx.x * 512 + threadIdx.x;
    int i1 = i0 + 256;
    int d0 = 0, d1 = 0;
    bool ok0 = (i0 < E), ok1 = (i1 < E);
    if (ok0) d0 = dst[i0];
    if (ok1) d1 = dst[i1];
    if (ok0) eseq[i0] = atomicAdd(&deg[d0], 1);
    if (ok1) eseq[i1] = atomicAdd(&deg[d1], 1);
}

// ---------------- scan pass 1: per-block sums ----------------
__global__ __launch_bounds__(256) void k_bsum(const int* __restrict__ deg,
                                              int* __restrict__ bsum) {
    __shared__ int red[256];
    int tid = threadIdx.x;
    int i = blockIdx.x * 256 + tid;
    red[tid] = (i < NN) ? deg[i] : 0;
    __syncthreads();
#pragma unroll
    for (int o = 128; o > 0; o >>= 1) {
        if (tid < o) red[tid] += red[tid + o];
        __syncthreads();
    }
    if (tid == 0) bsum[blockIdx.x] = red[0];
}

// ---------------- scan pass 2: block prefix + local scan + dinv ----------------
__global__ __launch_bounds__(256) void k_scan2(const int* __restrict__ deg,
                                               const int* __restrict__ bsum,
                                               int* __restrict__ off,
                                               float* __restrict__ dinv) {
    __shared__ int part[256];
    __shared__ int bpref;
    int tid = threadIdx.x;
    int i = blockIdx.x * 256 + tid;

    part[tid] = (tid < NB && tid < blockIdx.x) ? bsum[tid] : 0;
    __syncthreads();
#pragma unroll
    for (int o = 128; o > 0; o >>= 1) {
        if (tid < o) part[tid] += part[tid + o];
        __syncthreads();
    }
    if (tid == 0) bpref = part[0];
    __syncthreads();
    int base = bpref;
    __syncthreads();

    int v = (i < NN) ? deg[i] : 0;
    part[tid] = v;
    __syncthreads();
#pragma unroll
    for (int o = 1; o < 256; o <<= 1) {
        int u = (tid >= o) ? part[tid - o] : 0;
        __syncthreads();
        part[tid] += u;
        __syncthreads();
    }
    int incl = part[tid];
    if (i < NN) {
        off[i]  = base + incl - v;                  // exclusive
        dinv[i] = rsqrtf((float)(v + 1));
    }
    if (i == NN - 1) off[NN] = base + incl;         // == E
}

// ---------------- CSR fill: atomic-free scatter ----------------
__global__ __launch_bounds__(256) void k_fill(const int* __restrict__ src,
                                              const int* __restrict__ dst, int E,
                                              const int* __restrict__ off,
                                              const int* __restrict__ eseq,
                                              int* __restrict__ csr_src) {
    int i = blockIdx.x * blockDim.x + threadIdx.x;
    if (i < E) {
        int d = dst[i];
        csr_src[off[d] + eseq[i]] = src[i];
    }
}

// ---------------- GEMM: 64x128 tile, 4x8 thread tile; stores h' = dinv*h (bf16) ----------------
#define BN 64
#define BK 32
__global__ __launch_bounds__(256) void k_gemm(const float* __restrict__ x,
                                              const float* __restrict__ W,
                                              const float* __restrict__ dinv,
                                              unsigned short* __restrict__ h) {
    __shared__ float xs[BK][BN + 4];
    __shared__ float ws[BK][CC + 4];
    int tid = threadIdx.x;
    int n0 = blockIdx.x * BN;

    int nl = tid & 63;
    int cl = tid >> 6;
    int n = n0 + nl;
    bool ok = (n < NN);
    int b = 0, t = 0;
    if (ok) { b = n / TT; t = n - b * TT; }
    const float* xp = x + ((size_t)b * CC) * TT + t;

    int wl = tid & 127;
    int wc = tid >> 7;

    int tx = tid & 15;
    int ty = tid >> 4;

    float acc[4][8];
#pragma unroll
    for (int i = 0; i < 4; ++i)
#pragma unroll
        for (int j = 0; j < 8; ++j) acc[i][j] = 0.f;

    for (int k0 = 0; k0 < CC; k0 += BK) {
#pragma unroll
        for (int i = 0; i < BK / 4; ++i) {
            int c = cl + i * 4;
            xs[c][nl] = ok ? xp[(size_t)(k0 + c) * TT] : 0.f;
        }
#pragma unroll
        for (int i = 0; i < BK / 2; ++i) {
            int c = wc + i * 2;
            ws[c][wl] = W[(k0 + c) * CC + wl];
        }
        __syncthreads();
#pragma unroll 8
        for (int k = 0; k < BK; ++k) {
            float4 a0 = *(const float4*)&xs[k][ty * 4];
            float4 b0 = *(const float4*)&ws[k][tx * 4];
            float4 b1 = *(const float4*)&ws[k][64 + tx * 4];
            acc[0][0] = fmaf(a0.x, b0.x, acc[0][0]); acc[0][1] = fmaf(a0.x, b0.y, acc[0][1]);
            acc[0][2] = fmaf(a0.x, b0.z, acc[0][2]); acc[0][3] = fmaf(a0.x, b0.w, acc[0][3]);
            acc[0][4] = fmaf(a0.x, b1.x, acc[0][4]); acc[0][5] = fmaf(a0.x, b1.y, acc[0][5]);
            acc[0][6] = fmaf(a0.x, b1.z, acc[0][6]); acc[0][7] = fmaf(a0.x, b1.w, acc[0][7]);
            acc[1][0] = fmaf(a0.y, b0.x, acc[1][0]); acc[1][1] = fmaf(a0.y, b0.y, acc[1][1]);
            acc[1][2] = fmaf(a0.y, b0.z, acc[1][2]); acc[1][3] = fmaf(a0.y, b0.w, acc[1][3]);
            acc[1][4] = fmaf(a0.y, b1.x, acc[1][4]); acc[1][5] = fmaf(a0.y, b1.y, acc[1][5]);
            acc[1][6] = fmaf(a0.y, b1.z, acc[1][6]); acc[1][7] = fmaf(a0.y, b1.w, acc[1][7]);
            acc[2][0] = fmaf(a0.z, b0.x, acc[2][0]); acc[2][1] = fmaf(a0.z, b0.y, acc[2][1]);
            acc[2][2] = fmaf(a0.z, b0.z, acc[2][2]); acc[2][3] = fmaf(a0.z, b0.w, acc[2][3]);
            acc[2][4] = fmaf(a0.z, b1.x, acc[2][4]); acc[2][5] = fmaf(a0.z, b1.y, acc[2][5]);
            acc[2][6] = fmaf(a0.z, b1.z, acc[2][6]); acc[2][7] = fmaf(a0.z, b1.w, acc[2][7]);
            acc[3][0] = fmaf(a0.w, b0.x, acc[3][0]); acc[3][1] = fmaf(a0.w, b0.y, acc[3][1]);
            acc[3][2] = fmaf(a0.w, b0.z, acc[3][2]); acc[3][3] = fmaf(a0.w, b0.w, acc[3][3]);
            acc[3][4] = fmaf(a0.w, b1.x, acc[3][4]); acc[3][5] = fmaf(a0.w, b1.y, acc[3][5]);
            acc[3][6] = fmaf(a0.w, b1.z, acc[3][6]); acc[3][7] = fmaf(a0.w, b1.w, acc[3][7]);
        }
        __syncthreads();
    }

#pragma unroll
    for (int i = 0; i < 4; ++i) {
        int no = n0 + ty * 4 + i;
        if (no < NN) {
            float di = dinv[no];
            ushort4 p0, p1;
            p0.x = f2bf(di * acc[i][0]); p0.y = f2bf(di * acc[i][1]);
            p0.z = f2bf(di * acc[i][2]); p0.w = f2bf(di * acc[i][3]);
            p1.x = f2bf(di * acc[i][4]); p1.y = f2bf(di * acc[i][5]);
            p1.z = f2bf(di * acc[i][6]); p1.w = f2bf(di * acc[i][7]);
            *(ushort4*)&h[(size_t)no * CC + tx * 4]      = p0;
            *(ushort4*)&h[(size_t)no * CC + 64 + tx * 4] = p1;
        }
    }
}

// ---------------- aggregation: one wave per node, unroll-8 CSR gather (pre-scaled bf16 h') ----------------
// out_n = dinv[n] * (sum_j h'[s_j] + h'[n]) + bias
__global__ __launch_bounds__(256) void k_agg(const unsigned int* __restrict__ hb,
                                             const int* __restrict__ off,
                                             const int* __restrict__ csr_src,
                                             const float* __restrict__ dinv,
                                             const float* __restrict__ bias,
                                             float* __restrict__ agg) {
    int lane = threadIdx.x & 63;
    int w    = threadIdx.x >> 6;
    int n    = blockIdx.x * 4 + w;
    if (n >= NN) return;
    float ax = 0.f, ay = 0.f;
    int e0 = off[n], e1 = off[n + 1];
    int e = e0;
    for (; e + 8 <= e1; e += 8) {
        int s0 = csr_src[e + 0], s1 = csr_src[e + 1], s2 = csr_src[e + 2], s3 = csr_src[e + 3];
        int s4 = csr_src[e + 4], s5 = csr_src[e + 5], s6 = csr_src[e + 6], s7 = csr_src[e + 7];
        unsigned int v0 = hb[(size_t)s0 * 64 + lane];
        unsigned int v1 = hb[(size_t)s1 * 64 + lane];
        unsigned int v2 = hb[(size_t)s2 * 64 + lane];
        unsigned int v3 = hb[(size_t)s3 * 64 + lane];
        unsigned int v4 = hb[(size_t)s4 * 64 + lane];
        unsigned int v5 = hb[(size_t)s5 * 64 + lane];
        unsigned int v6 = hb[(size_t)s6 * 64 + lane];
        unsigned int v7 = hb[(size_t)s7 * 64 + lane];
        ax += bfhi(v0); ay += bflo(v0);
        ax += bfhi(v1); ay += bflo(v1);
        ax += bfhi(v2); ay += bflo(v2);
        ax += bfhi(v3); ay += bflo(v3);
        ax += bfhi(v4); ay += bflo(v4);
        ax += bfhi(v5); ay += bflo(v5);
        ax += bfhi(v6); ay += bflo(v6);
        ax += bfhi(v7); ay += bflo(v7);
    }
    for (; e < e1; ++e) {
        int s = csr_src[e];
        unsigned int v = hb[(size_t)s * 64 + lane];
        ax += bfhi(v); ay += bflo(v);
    }
    unsigned int hv = hb[(size_t)n * 64 + lane];
    ax += bfhi(hv);
    ay += bflo(hv);
    float di = dinv[n];
    const float2* b2 = (const float2*)bias;
    float2 bb = b2[lane];
    float rx = fmaxf(fmaf(di, ax, bb.x), 0.f);
    float ry = fmaxf(fmaf(di, ay, bb.y), 0.f);
    ((float2*)agg)[(size_t)n * 64 + lane] = make_float2(rx, ry);
}

// ---------------- transpose [n][oc] -> [b][oc][t] ----------------
__global__ void k_trans(const float* __restrict__ agg, float* __restrict__ out) {
    __shared__ float tile[32][33];
    int t0 = blockIdx.x * 32;
    int o0 = blockIdx.y * 32;
    int b  = blockIdx.z;
    int tx = threadIdx.x, ty = threadIdx.y;         // 32 x 8
#pragma unroll
    for (int i = 0; i < 4; ++i) {
        int t = t0 + ty + i * 8;
        if (t < TT) tile[ty + i * 8][tx] = agg[(size_t)(b * TT + t) * CC + o0 + tx];
    }
    __syncthreads();
#pragma unroll
    for (int i = 0; i < 4; ++i) {
        int t  = t0 + tx;
        int oc = o0 + ty + i * 8;
        if (t < TT) out[((size_t)b * CC + oc) * TT + t] = tile[tx][ty + i * 8];
    }
}

extern "C" void kernel_launch(void* const* d_in, const int* in_sizes, int n_in,
                              void* d_out, int out_size, void* d_ws, size_t ws_size,
                              hipStream_t stream) {
    const float* x    = (const float*)d_in[0];
    const float* W    = (const float*)d_in[1];
    const float* bias = (const float*)d_in[2];
    const int*   ei   = (const int*)d_in[3];
    int E = in_sizes[3] / 2;
    const int* src = ei;
    const int* dst = ei + E;
    float* out = (float*)d_out;

    char* ws = (char*)d_ws;
    size_t o = 0;
    unsigned short* h = (unsigned short*)(ws + o); o += (size_t)NN * CC * 2;  // 12.8 MB
    float* agg  = (float*)(ws + o); o += (size_t)NN * CC * 4;                 // 25.6 MB
    int*   deg  = (int*)  (ws + o); o += (size_t)NN * 4;
    float* dinv = (float*)(ws + o); o += (size_t)NN * 4;
    int*   off  = (int*)  (ws + o); o += (size_t)(NN + 1) * 4 + 12;
    int*   bsum = (int*)  (ws + o); o += (size_t)((NB + 3) & ~3) * 4;
    int*   eseq = (int*)  (ws + o); o += (size_t)E * 4;
    int*   csrs = (int*)  (ws + o); o += (size_t)E * 4;

    hipMemsetAsync(deg, 0, (size_t)NN * 4, stream);

    k_deg  <<<(E + 511) / 512, 256, 0, stream>>>(dst, E, deg, eseq);
    k_bsum <<<NB, 256, 0, stream>>>(deg, bsum);
    k_scan2<<<NB, 256, 0, stream>>>(deg, bsum, off, dinv);
    k_fill <<<(E + 255) / 256, 256, 0, stream>>>(src, dst, E, off, eseq, csrs);
    k_gemm <<<(NN + BN - 1) / BN, 256, 0, stream>>>(x, W, dinv, h);
    k_agg  <<<(NN + 3) / 4, 256, 0, stream>>>((const unsigned int*)h, off, csrs, dinv, bias, agg);
    dim3 tg((TT + 31) / 32, CC / 32, BB);
    k_trans<<<tg, dim3(32, 8), 0, stream>>>(agg, out);
}

// Round 9
// 206.265 us; speedup vs baseline: 1.1865x; 1.0466x over previous
//
#include <hip/hip_runtime.h>

#define TT 25000
#define BB 2
#define CC 128
#define NN (BB*TT)   // 50000 nodes
#define NB ((NN + 255) / 256)  // 196 scan blocks

__device__ inline unsigned short f2bf(float f) {
    unsigned int u = __float_as_uint(f);
    u += 0x7FFF + ((u >> 16) & 1);          // round-to-nearest-even
    return (unsigned short)(u >> 16);
}
__device__ inline float bfhi(unsigned int v) { return __uint_as_float(v << 16); }
__device__ inline float bflo(unsigned int v) { return __uint_as_float(v & 0xFFFF0000u); }

// ---------------- degree count + per-edge sequence number ----------------
__global__ __launch_bounds__(256) void k_deg(const int* __restrict__ dst, int E,
                                             int* __restrict__ deg,
                                             int* __restrict__ eseq) {
    int i0 = blockIdx.x * 512 + threadIdx.x;
    int i1 = i0 + 256;
    int d0 = 0, d1 = 0;
    bool ok0 = (i0 < E), ok1 = (i1 < E);
    if (ok0) d0 = dst[i0];
    if (ok1) d1 = dst[i1];
    if (ok0) eseq[i0] = atomicAdd(&deg[d0], 1);
    if (ok1) eseq[i1] = atomicAdd(&deg[d1], 1);
}

// ---------------- scan pass 1: per-block sums ----------------
__global__ __launch_bounds__(256) void k_bsum(const int* __restrict__ deg,
                                              int* __restrict__ bsum) {
    __shared__ int red[256];
    int tid = threadIdx.x;
    int i = blockIdx.x * 256 + tid;
    red[tid] = (i < NN) ? deg[i] : 0;
    __syncthreads();
#pragma unroll
    for (int o = 128; o > 0; o >>= 1) {
        if (tid < o) red[tid] += red[tid + o];
        __syncthreads();
    }
    if (tid == 0) bsum[blockIdx.x] = red[0];
}

// ---------------- scan pass 2: block prefix + local scan + dinv ----------------
__global__ __launch_bounds__(256) void k_scan2(const int* __restrict__ deg,
                                               const int* __restrict__ bsum,
                                               int* __restrict__ off,
                                               float* __restrict__ dinv) {
    __shared__ int part[256];
    __shared__ int bpref;
    int tid = threadIdx.x;
    int i = blockIdx.x * 256 + tid;

    part[tid] = (tid < NB && tid < blockIdx.x) ? bsum[tid] : 0;
    __syncthreads();
#pragma unroll
    for (int o = 128; o > 0; o >>= 1) {
        if (tid < o) part[tid] += part[tid + o];
        __syncthreads();
    }
    if (tid == 0) bpref = part[0];
    __syncthreads();
    int base = bpref;
    __syncthreads();

    int v = (i < NN) ? deg[i] : 0;
    part[tid] = v;
    __syncthreads();
#pragma unroll
    for (int o = 1; o < 256; o <<= 1) {
        int u = (tid >= o) ? part[tid - o] : 0;
        __syncthreads();
        part[tid] += u;
        __syncthreads();
    }
    int incl = part[tid];
    if (i < NN) {
        off[i]  = base + incl - v;                  // exclusive
        dinv[i] = rsqrtf((float)(v + 1));
    }
    if (i == NN - 1) off[NN] = base + incl;         // == E
}

// ---------------- CSR fill: atomic-free scatter ----------------
__global__ __launch_bounds__(256) void k_fill(const int* __restrict__ src,
                                              const int* __restrict__ dst, int E,
                                              const int* __restrict__ off,
                                              const int* __restrict__ eseq,
                                              int* __restrict__ csr_src) {
    int i = blockIdx.x * blockDim.x + threadIdx.x;
    if (i < E) {
        int d = dst[i];
        csr_src[off[d] + eseq[i]] = src[i];
    }
}

// ---------------- GEMM: 64x128 tile, 4x8 thread tile; stores h' = dinv*h (bf16) ----------------
#define BN 64
#define BK 32
__global__ __launch_bounds__(256) void k_gemm(const float* __restrict__ x,
                                              const float* __restrict__ W,
                                              const float* __restrict__ dinv,
                                              unsigned short* __restrict__ h) {
    __shared__ float xs[BK][BN + 4];
    __shared__ float ws[BK][CC + 4];
    int tid = threadIdx.x;
    int n0 = blockIdx.x * BN;

    int nl = tid & 63;
    int cl = tid >> 6;
    int n = n0 + nl;
    bool ok = (n < NN);
    int b = 0, t = 0;
    if (ok) { b = n / TT; t = n - b * TT; }
    const float* xp = x + ((size_t)b * CC) * TT + t;

    int wl = tid & 127;
    int wc = tid >> 7;

    int tx = tid & 15;
    int ty = tid >> 4;

    float acc[4][8];
#pragma unroll
    for (int i = 0; i < 4; ++i)
#pragma unroll
        for (int j = 0; j < 8; ++j) acc[i][j] = 0.f;

    for (int k0 = 0; k0 < CC; k0 += BK) {
#pragma unroll
        for (int i = 0; i < BK / 4; ++i) {
            int c = cl + i * 4;
            xs[c][nl] = ok ? xp[(size_t)(k0 + c) * TT] : 0.f;
        }
#pragma unroll
        for (int i = 0; i < BK / 2; ++i) {
            int c = wc + i * 2;
            ws[c][wl] = W[(k0 + c) * CC + wl];
        }
        __syncthreads();
#pragma unroll 8
        for (int k = 0; k < BK; ++k) {
            float4 a0 = *(const float4*)&xs[k][ty * 4];
            float4 b0 = *(const float4*)&ws[k][tx * 4];
            float4 b1 = *(const float4*)&ws[k][64 + tx * 4];
            acc[0][0] = fmaf(a0.x, b0.x, acc[0][0]); acc[0][1] = fmaf(a0.x, b0.y, acc[0][1]);
            acc[0][2] = fmaf(a0.x, b0.z, acc[0][2]); acc[0][3] = fmaf(a0.x, b0.w, acc[0][3]);
            acc[0][4] = fmaf(a0.x, b1.x, acc[0][4]); acc[0][5] = fmaf(a0.x, b1.y, acc[0][5]);
            acc[0][6] = fmaf(a0.x, b1.z, acc[0][6]); acc[0][7] = fmaf(a0.x, b1.w, acc[0][7]);
            acc[1][0] = fmaf(a0.y, b0.x, acc[1][0]); acc[1][1] = fmaf(a0.y, b0.y, acc[1][1]);
            acc[1][2] = fmaf(a0.y, b0.z, acc[1][2]); acc[1][3] = fmaf(a0.y, b0.w, acc[1][3]);
            acc[1][4] = fmaf(a0.y, b1.x, acc[1][4]); acc[1][5] = fmaf(a0.y, b1.y, acc[1][5]);
            acc[1][6] = fmaf(a0.y, b1.z, acc[1][6]); acc[1][7] = fmaf(a0.y, b1.w, acc[1][7]);
            acc[2][0] = fmaf(a0.z, b0.x, acc[2][0]); acc[2][1] = fmaf(a0.z, b0.y, acc[2][1]);
            acc[2][2] = fmaf(a0.z, b0.z, acc[2][2]); acc[2][3] = fmaf(a0.z, b0.w, acc[2][3]);
            acc[2][4] = fmaf(a0.z, b1.x, acc[2][4]); acc[2][5] = fmaf(a0.z, b1.y, acc[2][5]);
            acc[2][6] = fmaf(a0.z, b1.z, acc[2][6]); acc[2][7] = fmaf(a0.z, b1.w, acc[2][7]);
            acc[3][0] = fmaf(a0.w, b0.x, acc[3][0]); acc[3][1] = fmaf(a0.w, b0.y, acc[3][1]);
            acc[3][2] = fmaf(a0.w, b0.z, acc[3][2]); acc[3][3] = fmaf(a0.w, b0.w, acc[3][3]);
            acc[3][4] = fmaf(a0.w, b1.x, acc[3][4]); acc[3][5] = fmaf(a0.w, b1.y, acc[3][5]);
            acc[3][6] = fmaf(a0.w, b1.z, acc[3][6]); acc[3][7] = fmaf(a0.w, b1.w, acc[3][7]);
        }
        __syncthreads();
    }

#pragma unroll
    for (int i = 0; i < 4; ++i) {
        int no = n0 + ty * 4 + i;
        if (no < NN) {
            float di = dinv[no];
            ushort4 p0, p1;
            p0.x = f2bf(di * acc[i][0]); p0.y = f2bf(di * acc[i][1]);
            p0.z = f2bf(di * acc[i][2]); p0.w = f2bf(di * acc[i][3]);
            p1.x = f2bf(di * acc[i][4]); p1.y = f2bf(di * acc[i][5]);
            p1.z = f2bf(di * acc[i][6]); p1.w = f2bf(di * acc[i][7]);
            *(ushort4*)&h[(size_t)no * CC + tx * 4]      = p0;
            *(ushort4*)&h[(size_t)no * CC + 64 + tx * 4] = p1;
        }
    }
}

// ---------------- aggregation: one wave per node; vectorized index fetch ----------------
// One lane-parallel load grabs up to 64 CSR indices; __shfl extracts them (no
// VMEM dependency), so 16 row gathers issue back-to-back per group.
// out_n = dinv[n] * (sum_j h'[s_j] + h'[n]) + bias
__global__ __launch_bounds__(256) void k_agg(const unsigned int* __restrict__ hb,
                                             const int* __restrict__ off,
                                             const int* __restrict__ csr_src,
                                             const float* __restrict__ dinv,
                                             const float* __restrict__ bias,
                                             float* __restrict__ agg) {
    int lane = threadIdx.x & 63;
    int w    = threadIdx.x >> 6;
    int n    = blockIdx.x * 4 + w;
    if (n >= NN) return;
    float ax = 0.f, ay = 0.f;
    int e0 = off[n], e1 = off[n + 1];

    for (int c0 = e0; c0 < e1; c0 += 64) {
        int cnt = e1 - c0; if (cnt > 64) cnt = 64;
        int li = lane < cnt ? lane : cnt - 1;
        int iv = csr_src[c0 + li];                  // 64 indices in one coalesced load
        int j = 0;
        for (; j + 16 <= cnt; j += 16) {
            int s[16];
#pragma unroll
            for (int u = 0; u < 16; ++u) s[u] = __shfl(iv, j + u, 64);
            unsigned int v[16];
#pragma unroll
            for (int u = 0; u < 16; ++u) v[u] = hb[(size_t)s[u] * 64 + lane];
#pragma unroll
            for (int u = 0; u < 16; ++u) { ax += bfhi(v[u]); ay += bflo(v[u]); }
        }
        for (; j + 4 <= cnt; j += 4) {
            int s[4];
#pragma unroll
            for (int u = 0; u < 4; ++u) s[u] = __shfl(iv, j + u, 64);
            unsigned int v[4];
#pragma unroll
            for (int u = 0; u < 4; ++u) v[u] = hb[(size_t)s[u] * 64 + lane];
#pragma unroll
            for (int u = 0; u < 4; ++u) { ax += bfhi(v[u]); ay += bflo(v[u]); }
        }
        for (; j < cnt; ++j) {
            int s = __shfl(iv, j, 64);
            unsigned int v = hb[(size_t)s * 64 + lane];
            ax += bfhi(v); ay += bflo(v);
        }
    }

    unsigned int hv = hb[(size_t)n * 64 + lane];    // self loop
    ax += bfhi(hv);
    ay += bflo(hv);
    float di = dinv[n];
    const float2* b2 = (const float2*)bias;
    float2 bb = b2[lane];
    float rx = fmaxf(fmaf(di, ax, bb.x), 0.f);
    float ry = fmaxf(fmaf(di, ay, bb.y), 0.f);
    ((float2*)agg)[(size_t)n * 64 + lane] = make_float2(rx, ry);
}

// ---------------- transpose [n][oc] -> [b][oc][t] ----------------
__global__ void k_trans(const float* __restrict__ agg, float* __restrict__ out) {
    __shared__ float tile[32][33];
    int t0 = blockIdx.x * 32;
    int o0 = blockIdx.y * 32;
    int b  = blockIdx.z;
    int tx = threadIdx.x, ty = threadIdx.y;         // 32 x 8
#pragma unroll
    for (int i = 0; i < 4; ++i) {
        int t = t0 + ty + i * 8;
        if (t < TT) tile[ty + i * 8][tx] = agg[(size_t)(b * TT + t) * CC + o0 + tx];
    }
    __syncthreads();
#pragma unroll
    for (int i = 0; i < 4; ++i) {
        int t  = t0 + tx;
        int oc = o0 + ty + i * 8;
        if (t < TT) out[((size_t)b * CC + oc) * TT + t] = tile[tx][ty + i * 8];
    }
}

extern "C" void kernel_launch(void* const* d_in, const int* in_sizes, int n_in,
                              void* d_out, int out_size, void* d_ws, size_t ws_size,
                              hipStream_t stream) {
    const float* x    = (const float*)d_in[0];
    const float* W    = (const float*)d_in[1];
    const float* bias = (const float*)d_in[2];
    const int*   ei   = (const int*)d_in[3];
    int E = in_sizes[3] / 2;
    const int* src = ei;
    const int* dst = ei + E;
    float* out = (float*)d_out;

    char* ws = (char*)d_ws;
    size_t o = 0;
    unsigned short* h = (unsigned short*)(ws + o); o += (size_t)NN * CC * 2;  // 12.8 MB
    float* agg  = (float*)(ws + o); o += (size_t)NN * CC * 4;                 // 25.6 MB
    int*   deg  = (int*)  (ws + o); o += (size_t)NN * 4;
    float* dinv = (float*)(ws + o); o += (size_t)NN * 4;
    int*   off  = (int*)  (ws + o); o += (size_t)(NN + 1) * 4 + 12;
    int*   bsum = (int*)  (ws + o); o += (size_t)((NB + 3) & ~3) * 4;
    int*   eseq = (int*)  (ws + o); o += (size_t)E * 4;
    int*   csrs = (int*)  (ws + o); o += (size_t)E * 4;

    hipMemsetAsync(deg, 0, (size_t)NN * 4, stream);

    k_deg  <<<(E + 511) / 512, 256, 0, stream>>>(dst, E, deg, eseq);
    k_bsum <<<NB, 256, 0, stream>>>(deg, bsum);
    k_scan2<<<NB, 256, 0, stream>>>(deg, bsum, off, dinv);
    k_fill <<<(E + 255) / 256, 256, 0, stream>>>(src, dst, E, off, eseq, csrs);
    k_gemm <<<(NN + BN - 1) / BN, 256, 0, stream>>>(x, W, dinv, h);
    k_agg  <<<(NN + 3) / 4, 256, 0, stream>>>((const unsigned int*)h, off, csrs, dinv, bias, agg);
    dim3 tg((TT + 31) / 32, CC / 32, BB);
    k_trans<<<tg, dim3(32, 8), 0, stream>>>(agg, out);
}